// Round 7
// baseline (34182.715 us; speedup 1.0000x reference)
//
#include <hip/hip_runtime.h>
#include <hip/hip_cooperative_groups.h>

namespace cg = cooperative_groups;

// Problem dims (fixed by the reference)
constexpr int B  = 128;
constexpr int SP = 128;
constexpr int SH = 64;
constexpr int H  = 1024;
constexpr int E  = 300;
constexpr int NC = 4;
constexpr int KCAT = E + H;     // 1324

__device__ __forceinline__ float sigf(float x) { return 1.0f / (1.0f + __expf(-x)); }
__device__ __forceinline__ float tanh_fast(float x) {
    float e = __expf(2.0f * x);
    return 1.0f - 2.0f / (e + 1.0f);
}

// ---------------------------------------------------------------------------
// Persistent cooperative LSTM: runs ALL nsteps with grid.sync() between steps.
// Per step: g = [emb_gather | h_in] @ [w_ih | w_hh]^T + biases, then cell.
// Tile: 32 rows x (16 hidden units x 4 gates), BK=32, LDS double-buffered.
// Grid MUST be (64,4)=256 blocks x 256 thr (1 block/CU, co-resident).
// ---------------------------------------------------------------------------
template<int PREMISE>
__global__ __launch_bounds__(256)
void lstm_seq_kernel(const int* __restrict__ tokens, int S, int nsteps,
                     const float* __restrict__ emb,
                     const float* __restrict__ w_ih,   // [4H][E]
                     const float* __restrict__ w_hh,   // [4H][H]
                     const float* __restrict__ b_ih,
                     const float* __restrict__ b_hh,
                     float* __restrict__ hA, float* __restrict__ hB,
                     float* __restrict__ c,
                     float* __restrict__ hmask, float* __restrict__ cmask,
                     float* __restrict__ seq_out)
{
    cg::grid_group grid = cg::this_grid();
    const int tid = threadIdx.x;
    const int tx = tid & 15;          // hidden unit j within tile
    const int ty = tid >> 4;          // m-pair
    const int k0 = blockIdx.x * 16;   // hidden-unit tile base
    const int m0 = blockIdx.y * 32;

    __shared__ float As[2][32][34];   // [q][m], stride 34 (float2-aligned)
    __shared__ float Bs[2][32][68];   // [q][j*4+g], stride 68 (float4-aligned)

    const int qa = tid & 31, ma = tid >> 5;   // A staging: q fast, rows ma+8r
    const int qb = tid & 31, ub = tid >> 5;   // B staging: q fast, cols ub+8rr

    // B row (gate-major weight row) for each staged col v = j*4+g
    int nrow[8];
#pragma unroll
    for (int rr = 0; rr < 8; ++rr) {
        int v = ub + 8 * rr;
        nrow[rr] = ((v & 3) << 10) + k0 + (v >> 2);
    }
    const int k = k0 + tx;
    float bsum[4];
#pragma unroll
    for (int g = 0; g < 4; ++g) bsum[g] = b_ih[g * H + k] + b_hh[g * H + k];

    constexpr int NKT = (KCAT + 31) / 32;   // 42

    for (int t = 0; t < nsteps; ++t) {
        const float* h_in = (t & 1) ? hB : hA;
        float* h_out      = (t & 1) ? hA : hB;
        int tokv[4];
#pragma unroll
        for (int r = 0; r < 4; ++r) tokv[r] = tokens[(m0 + ma + 8 * r) * S + t];

        auto ldA = [&](int q0, int r) -> float {
            int q = q0 + qa;
            if (q < E)    return emb[(size_t)tokv[r] * E + q];
            if (q < KCAT) return h_in[(size_t)(m0 + ma + 8 * r) * H + (q - E)];
            return 0.f;
        };
        auto ldB = [&](int q0, int rr) -> float {
            int q = q0 + qb;
            int n = nrow[rr];
            if (q < E)    return w_ih[(size_t)n * E + q];
            if (q < KCAT) return w_hh[(size_t)n * H + (q - E)];
            return 0.f;
        };

        float ra[4], rb[8];
#pragma unroll
        for (int r = 0; r < 4; ++r) ra[r] = ldA(0, r);
#pragma unroll
        for (int rr = 0; rr < 8; ++rr) rb[rr] = ldB(0, rr);
#pragma unroll
        for (int r = 0; r < 4; ++r) As[0][qa][ma + 8 * r] = ra[r];
#pragma unroll
        for (int rr = 0; rr < 8; ++rr) Bs[0][qb][ub + 8 * rr] = rb[rr];
        __syncthreads();

        float acc[2][4] = {};
        for (int kt = 0; kt < NKT; ++kt) {
            const int buf = kt & 1;
            if (kt + 1 < NKT) {
                int q0 = (kt + 1) * 32;
#pragma unroll
                for (int r = 0; r < 4; ++r) ra[r] = ldA(q0, r);
#pragma unroll
                for (int rr = 0; rr < 8; ++rr) rb[rr] = ldB(q0, rr);
            }
#pragma unroll
            for (int kk = 0; kk < 32; ++kk) {
                float2 a2 = *(const float2*)&As[buf][kk][ty * 2];
                float4 b4 = *(const float4*)&Bs[buf][kk][tx * 4];
                acc[0][0] += a2.x * b4.x; acc[0][1] += a2.x * b4.y;
                acc[0][2] += a2.x * b4.z; acc[0][3] += a2.x * b4.w;
                acc[1][0] += a2.y * b4.x; acc[1][1] += a2.y * b4.y;
                acc[1][2] += a2.y * b4.z; acc[1][3] += a2.y * b4.w;
            }
            if (kt + 1 < NKT) {
                const int nxt = buf ^ 1;
#pragma unroll
                for (int r = 0; r < 4; ++r) As[nxt][qa][ma + 8 * r] = ra[r];
#pragma unroll
                for (int rr = 0; rr < 8; ++rr) Bs[nxt][qb][ub + 8 * rr] = rb[rr];
                __syncthreads();
            }
        }

        // ---- cell epilogue: thread owns (m = m0+ty*2+i, k), all 4 gates ----
#pragma unroll
        for (int i = 0; i < 2; ++i) {
            int m = m0 + ty * 2 + i;
            size_t idx = (size_t)m * H + k;
            float i_ = sigf(acc[i][0] + bsum[0]);
            float f_ = sigf(acc[i][1] + bsum[1]);
            float g_ = tanh_fast(acc[i][2] + bsum[2]);
            float o_ = sigf(acc[i][3] + bsum[3]);
            float c2 = f_ * c[idx] + i_ * g_;
            float h2 = o_ * tanh_fast(c2);
            c[idx] = c2;
            h_out[idx] = h2;
            float mt = (tokens[m * S + t] != 0) ? 1.f : 0.f;
            float hmv = mt * h2 + (1.f - mt) * hmask[idx];
            hmask[idx] = hmv;
            if (PREMISE) {
                float cmv = mt * c2 + (1.f - mt) * cmask[idx];
                cmask[idx] = cmv;
                seq_out[((size_t)m * SP + t) * H + k] = hmv;   // Y [B][SP][H]
            } else {
                seq_out[((size_t)t * B + m) * H + k] = hmv;    // outh [SH][B][H]
            }
        }
        __threadfence();
        grid.sync();
    }
}

// ---------------------------------------------------------------------------
// 64x64-tile SGEMM, BK=16, dbuf (wide-parallel use: first = Y@wy, hsec = outh@wh).
// ---------------------------------------------------------------------------
__global__ __launch_bounds__(256)
void gemm64_kernel(const float* __restrict__ A, const float* __restrict__ Bw,
                   float* __restrict__ C, int M, int N, int K)
{
    const int tid = threadIdx.x;
    const int tx = tid & 15, ty = tid >> 4;
    const int n0 = blockIdx.x * 64, m0 = blockIdx.y * 64;
    __shared__ float As[2][16][68];
    __shared__ float Bs[2][16][68];
    const int ka = tid & 15, ma = tid >> 4;
    const int nb = tid & 63, kb = tid >> 6;

    float ra[4], rb[4];
    auto ldA = [&](int k0q, int r) -> float {
        int kq = k0q + ka;
        return (kq < K) ? A[(size_t)(m0 + ma + 16 * r) * K + kq] : 0.f;
    };
    auto ldB = [&](int k0q, int r) -> float {
        int kq = k0q + kb + 4 * r;
        return (kq < K) ? Bw[(size_t)kq * N + n0 + nb] : 0.f;
    };

    float acc[4][4] = {};
#pragma unroll
    for (int r = 0; r < 4; ++r) { ra[r] = ldA(0, r); rb[r] = ldB(0, r); }
#pragma unroll
    for (int r = 0; r < 4; ++r) { As[0][ka][ma + 16 * r] = ra[r]; Bs[0][kb + 4 * r][nb] = rb[r]; }
    __syncthreads();

    const int NKT = (K + 15) / 16;
    for (int kt = 0; kt < NKT; ++kt) {
        const int buf = kt & 1;
        if (kt + 1 < NKT) {
            int k0q = (kt + 1) * 16;
#pragma unroll
            for (int r = 0; r < 4; ++r) { ra[r] = ldA(k0q, r); rb[r] = ldB(k0q, r); }
        }
#pragma unroll
        for (int kk = 0; kk < 16; ++kk) {
            float4 a4 = *(const float4*)&As[buf][kk][ty * 4];
            float4 b4 = *(const float4*)&Bs[buf][kk][tx * 4];
            float av[4] = {a4.x, a4.y, a4.z, a4.w};
            float bv[4] = {b4.x, b4.y, b4.z, b4.w};
#pragma unroll
            for (int i = 0; i < 4; ++i)
#pragma unroll
                for (int j = 0; j < 4; ++j) acc[i][j] += av[i] * bv[j];
        }
        if (kt + 1 < NKT) {
            const int nxt = buf ^ 1;
#pragma unroll
            for (int r = 0; r < 4; ++r) { As[nxt][ka][ma + 16 * r] = ra[r]; Bs[nxt][kb + 4 * r][nb] = rb[r]; }
            __syncthreads();
        }
    }
#pragma unroll
    for (int i = 0; i < 4; ++i) {
        int m = m0 + ty * 4 + i;
        float4 v = make_float4(acc[i][0], acc[i][1], acc[i][2], acc[i][3]);
        *(float4*)&C[(size_t)m * N + n0 + tx * 4] = v;
    }
}

// ---------------------------------------------------------------------------
// Skinny GEMM (M=128): tile 32x64, BK=32, dbuf. Dual: bx<ntiles -> B1/C1 else B2/C2.
// K, N multiples of 32/64. B is [K][N] row-major.
// ---------------------------------------------------------------------------
template<bool ACC>
__global__ __launch_bounds__(256)
void skinny_kernel(const float* __restrict__ A,
                   const float* __restrict__ B1, float* __restrict__ C1,
                   const float* __restrict__ B2, float* __restrict__ C2,
                   int K, int N, int ntiles)
{
    const int tid = threadIdx.x;
    const int tx = tid & 15, ty = tid >> 4;
    const int bx = blockIdx.x;
    const float* Bw = (bx < ntiles) ? B1 : B2;
    float* C       = (bx < ntiles) ? C1 : C2;
    const int n0 = ((bx < ntiles) ? bx : bx - ntiles) * 64;
    const int m0 = blockIdx.y * 32;

    __shared__ float As[2][32][34];
    __shared__ float Bs[2][32][68];
    const int qa = tid & 31, ma = tid >> 5;   // A staging
    const int nb = tid & 63, kb = tid >> 6;   // B staging

    float ra[4], rb[8];
    auto ldA = [&](int k0q, int r) -> float {
        return A[(size_t)(m0 + ma + 8 * r) * K + k0q + qa];
    };
    auto ldB = [&](int k0q, int r) -> float {
        return Bw[(size_t)(k0q + kb + 4 * r) * N + n0 + nb];
    };

    float acc[2][4] = {};
#pragma unroll
    for (int r = 0; r < 4; ++r) ra[r] = ldA(0, r);
#pragma unroll
    for (int r = 0; r < 8; ++r) rb[r] = ldB(0, r);
#pragma unroll
    for (int r = 0; r < 4; ++r) As[0][qa][ma + 8 * r] = ra[r];
#pragma unroll
    for (int r = 0; r < 8; ++r) Bs[0][kb + 4 * r][nb] = rb[r];
    __syncthreads();

    const int NKT = K / 32;
    for (int kt = 0; kt < NKT; ++kt) {
        const int buf = kt & 1;
        if (kt + 1 < NKT) {
            int k0q = (kt + 1) * 32;
#pragma unroll
            for (int r = 0; r < 4; ++r) ra[r] = ldA(k0q, r);
#pragma unroll
            for (int r = 0; r < 8; ++r) rb[r] = ldB(k0q, r);
        }
#pragma unroll
        for (int kk = 0; kk < 32; ++kk) {
            float2 a2 = *(const float2*)&As[buf][kk][ty * 2];
            float4 b4 = *(const float4*)&Bs[buf][kk][tx * 4];
            acc[0][0] += a2.x * b4.x; acc[0][1] += a2.x * b4.y;
            acc[0][2] += a2.x * b4.z; acc[0][3] += a2.x * b4.w;
            acc[1][0] += a2.y * b4.x; acc[1][1] += a2.y * b4.y;
            acc[1][2] += a2.y * b4.z; acc[1][3] += a2.y * b4.w;
        }
        if (kt + 1 < NKT) {
            const int nxt = buf ^ 1;
#pragma unroll
            for (int r = 0; r < 4; ++r) As[nxt][qa][ma + 8 * r] = ra[r];
#pragma unroll
            for (int r = 0; r < 8; ++r) Bs[nxt][kb + 4 * r][nb] = rb[r];
            __syncthreads();
        }
    }
#pragma unroll
    for (int i = 0; i < 2; ++i) {
        int m = m0 + ty * 2 + i;
        float* cp = &C[(size_t)m * N + n0 + tx * 4];
        float4 v = make_float4(acc[i][0], acc[i][1], acc[i][2], acc[i][3]);
        if (ACC) {
            float4 o = *(const float4*)cp;
            v.x += o.x; v.y += o.y; v.z += o.z; v.w += o.w;
        }
        *(float4*)cp = v;
    }
}

// ---------------------------------------------------------------------------
// score: s[b,p] = sum_h tanh(first[b,p,h] + hsec_t[b,h] + secr[b,h]) * w[h]
//        + (-1000 on premise pads).
// ---------------------------------------------------------------------------
__global__ __launch_bounds__(256)
void score_kernel(const float* __restrict__ first,
                  const float* __restrict__ hsec_t,
                  const float* __restrict__ secr,
                  const float* __restrict__ w,
                  const int* __restrict__ ptoks,
                  float* __restrict__ s)
{
    const int bp = blockIdx.x;
    const int b = bp >> 7;
    const float* fr = first + (size_t)bp * H;
    const float* hs = hsec_t + (size_t)b * H;
    const float* sr = secr + (size_t)b * H;
    float acc = 0.f;
#pragma unroll
    for (int j = 0; j < 4; ++j) {
        int k = threadIdx.x + j * 256;
        acc += tanh_fast(fr[k] + hs[k] + sr[k]) * w[k];
    }
    for (int off = 32; off > 0; off >>= 1) acc += __shfl_down(acc, off);
    __shared__ float red[4];
    if ((threadIdx.x & 63) == 0) red[threadIdx.x >> 6] = acc;
    __syncthreads();
    if (threadIdx.x == 0) {
        float v = red[0] + red[1] + red[2] + red[3];
        int p = bp & 127;
        s[bp] = v + ((ptoks[b * SP + p] != 0) ? 0.f : -1000.f);
    }
}

// ---------------------------------------------------------------------------
// r_update (grid (B,2)): alpha = softmax(s[b,:]) (redundant per half);
// r_new = alpha @ Y[b] + tanh(rwt[b]); masked carry into r. Each block: 512 cols.
// ---------------------------------------------------------------------------
__global__ __launch_bounds__(256)
void r_update_kernel(const float* __restrict__ s,
                     const float* __restrict__ Y,
                     const float* __restrict__ rwt,
                     const int* __restrict__ htoks, int t,
                     float* __restrict__ r)
{
    const int b = blockIdx.x, half = blockIdx.y, tid = threadIdx.x;
    __shared__ float al[SP];
    __shared__ float red[SP];
    if (tid < SP) { float v = s[b * SP + tid]; al[tid] = v; red[tid] = v; }
    __syncthreads();
    for (int off = 64; off > 0; off >>= 1) {
        if (tid < off) red[tid] = fmaxf(red[tid], red[tid + off]);
        __syncthreads();
    }
    float mx = red[0];
    __syncthreads();
    if (tid < SP) { al[tid] = __expf(al[tid] - mx); red[tid] = al[tid]; }
    __syncthreads();
    for (int off = 64; off > 0; off >>= 1) {
        if (tid < off) red[tid] += red[tid + off];
        __syncthreads();
    }
    float inv = 1.f / red[0];
    __syncthreads();
    if (tid < SP) al[tid] *= inv;
    __syncthreads();

    float acc[2] = {0.f, 0.f};
    const float* Yb = Y + (size_t)b * SP * H + half * 512;
    for (int p = 0; p < SP; ++p) {
        float a = al[p];
        const float* yr = Yb + (size_t)p * H;
        acc[0] += a * yr[tid];
        acc[1] += a * yr[tid + 256];
    }
    float mt = (htoks[b * SH + t] != 0) ? 1.f : 0.f;
#pragma unroll
    for (int j = 0; j < 2; ++j) {
        int kg = half * 512 + tid + j * 256;
        float rnew = acc[j] + tanh_fast(rwt[(size_t)b * H + kg]);
        r[(size_t)b * H + kg] = mt * rnew + (1.f - mt) * r[(size_t)b * H + kg];
    }
}

// logits -> softmax over 4 classes -> fp32 out
__global__ __launch_bounds__(256)
void final_kernel(const float* __restrict__ pre,
                  const float* __restrict__ fc_w,
                  const float* __restrict__ fc_b,
                  float* __restrict__ out)
{
    int b = blockIdx.x;
    float acc[NC] = {0.f, 0.f, 0.f, 0.f};
    for (int k = threadIdx.x; k < H; k += 256) {
        float hs = tanh_fast(pre[(size_t)b * H + k]);
#pragma unroll
        for (int cc = 0; cc < NC; ++cc) acc[cc] += hs * fc_w[cc * H + k];
    }
    __shared__ float red[NC][256];
#pragma unroll
    for (int cc = 0; cc < NC; ++cc) red[cc][threadIdx.x] = acc[cc];
    __syncthreads();
    for (int off = 128; off > 0; off >>= 1) {
        if (threadIdx.x < off)
#pragma unroll
            for (int cc = 0; cc < NC; ++cc)
                red[cc][threadIdx.x] += red[cc][threadIdx.x + off];
        __syncthreads();
    }
    if (threadIdx.x == 0) {
        float l[NC], mx = -1e30f;
#pragma unroll
        for (int cc = 0; cc < NC; ++cc) { l[cc] = red[cc][0] + fc_b[cc]; mx = fmaxf(mx, l[cc]); }
        float sum = 0.f;
#pragma unroll
        for (int cc = 0; cc < NC; ++cc) { l[cc] = __expf(l[cc] - mx); sum += l[cc]; }
#pragma unroll
        for (int cc = 0; cc < NC; ++cc) out[b * NC + cc] = l[cc] / sum;
    }
}

extern "C" void kernel_launch(void* const* d_in, const int* in_sizes, int n_in,
                              void* d_out, int out_size, void* d_ws, size_t ws_size,
                              hipStream_t stream)
{
    const int*   prem   = (const int*)d_in[0];
    const int*   hyp    = (const int*)d_in[1];
    const float* emb    = (const float*)d_in[2];
    const float* w_ih_p = (const float*)d_in[3];
    const float* w_hh_p = (const float*)d_in[4];
    const float* b_ih_p = (const float*)d_in[5];
    const float* b_hh_p = (const float*)d_in[6];
    const float* w_ih_h = (const float*)d_in[7];
    const float* w_hh_h = (const float*)d_in[8];
    const float* b_ih_h = (const float*)d_in[9];
    const float* b_hh_h = (const float*)d_in[10];
    const float* wy     = (const float*)d_in[11];
    const float* wh     = (const float*)d_in[12];
    const float* wr     = (const float*)d_in[13];
    const float* wv     = (const float*)d_in[14];
    const float* wt     = (const float*)d_in[15];
    const float* wp     = (const float*)d_in[16];
    const float* wx     = (const float*)d_in[17];
    const float* fc_w   = (const float*)d_in[18];
    const float* fc_b   = (const float*)d_in[19];
    float* out = (float*)d_out;
    (void)in_sizes; (void)n_in; (void)out_size; (void)ws_size;

    char* wsc = (char*)d_ws;
    size_t off = 0;
    auto alloc = [&](size_t bytes) {
        void* p = wsc + off;
        off += (bytes + 255) & ~(size_t)255;
        return (float*)p;
    };
    float* Y     = alloc((size_t)B * SP * H * 4);   // [B][SP][H]
    float* first = alloc((size_t)B * SP * H * 4);   // Y @ wy
    float* outh  = alloc((size_t)SH * B * H * 4);   // [SH][B][H]
    float* hsec  = alloc((size_t)SH * B * H * 4);   // outh @ wh
    float* h0    = alloc((size_t)B * H * 4);        // h ping
    float* h1    = alloc((size_t)B * H * 4);        // h pong
    float* cbuf  = alloc((size_t)B * H * 4);
    float* hm    = alloc((size_t)B * H * 4);
    float* cm    = alloc((size_t)B * H * 4);
    float* r     = alloc((size_t)B * H * 4);
    float* secr  = alloc((size_t)B * H * 4);
    float* rwt   = alloc((size_t)B * H * 4);
    float* pre   = alloc((size_t)B * H * 4);
    float* sc    = alloc((size_t)B * SP * 4);

    const size_t BH = (size_t)B * H * sizeof(float);
    hipMemsetAsync(h0, 0, 5 * BH, stream);          // h0,h1,cbuf,hm,cm contiguous

    // -------- premise LSTM: ONE cooperative launch, 128 internal steps --------
    {
        int Sv = SP, nst = SP;
        void* args[] = {(void*)&prem, (void*)&Sv, (void*)&nst, (void*)&emb,
                        (void*)&w_ih_p, (void*)&w_hh_p, (void*)&b_ih_p, (void*)&b_hh_p,
                        (void*)&h0, (void*)&h1, (void*)&cbuf, (void*)&hm, (void*)&cm,
                        (void*)&Y};
        hipLaunchCooperativeKernel(reinterpret_cast<const void*>(&lstm_seq_kernel<1>),
                                   dim3(64, 4), dim3(256), args, 0, stream);
    }

    // -------- hypothesis LSTM: h=0, c = cm (masked last premise cell) --------
    hipMemsetAsync(h0, 0, 2 * BH, stream);
    hipMemsetAsync(hm, 0, BH, stream);
    {
        int Sv = SH, nst = SH;
        float* nullf = nullptr;
        void* args[] = {(void*)&hyp, (void*)&Sv, (void*)&nst, (void*)&emb,
                        (void*)&w_ih_h, (void*)&w_hh_h, (void*)&b_ih_h, (void*)&b_hh_h,
                        (void*)&h0, (void*)&h1, (void*)&cm, (void*)&hm, (void*)&nullf,
                        (void*)&outh};
        hipLaunchCooperativeKernel(reinterpret_cast<const void*>(&lstm_seq_kernel<0>),
                                   dim3(64, 4), dim3(256), args, 0, stream);
    }
    // hm = out_h_last

    // -------- hoisted wide GEMMs --------
    gemm64_kernel<<<dim3(H / 64, (B * SP) / 64), 256, 0, stream>>>(Y, wy, first, B * SP, H, H);
    gemm64_kernel<<<dim3(H / 64, (SH * B) / 64), 256, 0, stream>>>(outh, wh, hsec, SH * B, H, H);

    // -------- attention scan --------
    hipMemsetAsync(r, 0, BH, stream);
    for (int t = 0; t < SH; ++t) {
        skinny_kernel<false><<<dim3(32, 4), 256, 0, stream>>>(r, wr, secr, wt, rwt, H, H, 16);
        score_kernel<<<B * SP, 256, 0, stream>>>(first, hsec + (size_t)t * B * H, secr, wv, prem, sc);
        r_update_kernel<<<dim3(B, 2), 256, 0, stream>>>(sc, Y, rwt, hyp, t, r);
    }

    // -------- final projection + softmax --------
    skinny_kernel<false><<<dim3(16, 4), 256, 0, stream>>>(r,  wp, pre, nullptr, nullptr, H, H, 16);
    skinny_kernel<true ><<<dim3(16, 4), 256, 0, stream>>>(hm, wx, pre, nullptr, nullptr, H, H, 16);
    final_kernel<<<B, 256, 0, stream>>>(pre, fc_w, fc_b, out);
}